// Round 1
// baseline (241.259 us; speedup 1.0000x reference)
//
#include <hip/hip_runtime.h>
#include <cstdint>
#include <cstddef>

// Problem dims (fixed by setup_inputs): b=4096, d=n=1024, k=4
#define NB 4096
#define ND 1024

typedef unsigned short ushortT;
typedef short short8 __attribute__((ext_vector_type(8)));
typedef float f32x4 __attribute__((ext_vector_type(4)));

__device__ __forceinline__ ushortT f2bf(float f) {
    unsigned u = __float_as_uint(f);
    u += 0x7FFFu + ((u >> 16) & 1u);      // round-to-nearest-even
    return (ushortT)(u >> 16);
}

// 256-thread block sum; result valid on thread 0.
__device__ __forceinline__ float block_sum_256(float v, float* red) {
    #pragma unroll
    for (int o = 32; o > 0; o >>= 1) v += __shfl_down(v, o, 64);
    int wave = threadIdx.x >> 6;
    if ((threadIdx.x & 63) == 0) red[wave] = v;
    __syncthreads();
    return red[0] + red[1] + red[2] + red[3];
}

// --- prep: x -> bf16, row norms ---------------------------------------------
__global__ void prep_x(const float* __restrict__ x, ushortT* __restrict__ xh,
                       float* __restrict__ xx) {
    __shared__ float red[4];
    int r = blockIdx.x;
    const float* row = x + (size_t)r * ND;
    ushortT* orow = xh + (size_t)r * ND;
    float s = 0.f;
    #pragma unroll
    for (int j = 0; j < 4; ++j) {
        int c = threadIdx.x + j * 256;
        float v = row[c];
        orow[c] = f2bf(v);
        s += v * v;
    }
    float tot = block_sum_256(s, red);
    if (threadIdx.x == 0) xx[r] = tot;
}

// --- prep: stack [mu; v0..v3] -> bf16 W[5][1024][1024]; mm[n]; vmu[n][4] ----
__global__ void prep_w(const float* __restrict__ mu, const float* __restrict__ v,
                       ushortT* __restrict__ W, float* __restrict__ mm,
                       float* __restrict__ vmu) {
    __shared__ float red[4];
    int bid = blockIdx.x;          // 0..5119
    int t = bid >> 10;             // panel 0..4
    int n = bid & 1023;
    const float* src = (t == 0) ? (mu + (size_t)n * ND)
                                : (v + ((size_t)n * 4 + (t - 1)) * ND);
    const float* murow = mu + (size_t)n * ND;
    ushortT* dst = W + ((size_t)t * 1024 + n) * ND;
    float s = 0.f;
    #pragma unroll
    for (int j = 0; j < 4; ++j) {
        int c = threadIdx.x + j * 256;
        float val = src[c];
        dst[c] = f2bf(val);
        s += val * murow[c];
    }
    float tot = block_sum_256(s, red);
    if (threadIdx.x == 0) {
        if (t == 0) mm[n] = tot;               // ||mu||^2
        else        vmu[n * 4 + (t - 1)] = tot; // v_k . mu
    }
}

// --- fused 5-panel HMU GEMM -------------------------------------------------
// Tile: 128(M) x 64(n-cols) x 5 panels, BK=64, 4 waves (256 thr).
// Wave w owns rows [w*32, w*32+32): acc[mf][nf][t], mf<2, nf<4, t<5.
// LDS XOR slot-swizzle: 16B slot p stores logical slot s = p ^ (row&7).
__launch_bounds__(256, 2)
__global__ void gemm_hmu(const ushortT* __restrict__ Xh, const ushortT* __restrict__ Wh,
                         const float* __restrict__ xx, const float* __restrict__ mm,
                         const float* __restrict__ vmu, const float* __restrict__ lam,
                         float* __restrict__ U) {
    __shared__ ushortT As[128 * 64];        // 16 KB
    __shared__ ushortT Bs[5 * 64 * 64];     // 40 KB
    const int tid = threadIdx.x;
    const int lane = tid & 63, wave = tid >> 6;
    const int n0 = (blockIdx.x & 15) * 64;
    const int m0 = (blockIdx.x >> 4) * 128;

    f32x4 acc[2][4][5];
    #pragma unroll
    for (int mf = 0; mf < 2; ++mf)
        #pragma unroll
        for (int nf = 0; nf < 4; ++nf)
            #pragma unroll
            for (int t = 0; t < 5; ++t)
                acc[mf][nf][t] = (f32x4){0.f, 0.f, 0.f, 0.f};

    for (int kt = 0; kt < 16; ++kt) {
        const int k0 = kt * 64;
        // stage A: 128 rows x 8 slots of 16B
        #pragma unroll
        for (int q = 0; q < 4; ++q) {
            int c = tid + 256 * q;
            int row = c >> 3, p = c & 7, s = p ^ (row & 7);
            uint4 d = *reinterpret_cast<const uint4*>(
                Xh + (size_t)(m0 + row) * ND + k0 + s * 8);
            *reinterpret_cast<uint4*>(&As[row * 64 + p * 8]) = d;
        }
        // stage B: 5 panels x 64 rows x 8 slots
        #pragma unroll
        for (int q = 0; q < 10; ++q) {
            int c = tid + 256 * q;
            int t = c >> 9, r = (c >> 3) & 63, p = c & 7, s = p ^ (r & 7);
            uint4 d = *reinterpret_cast<const uint4*>(
                Wh + ((size_t)t * 1024 + n0 + r) * ND + k0 + s * 8);
            *reinterpret_cast<uint4*>(&Bs[(t * 64 + r) * 64 + p * 8]) = d;
        }
        __syncthreads();
        #pragma unroll
        for (int i = 0; i < 2; ++i) {       // two K=32 sub-steps
            short8 av[2];
            #pragma unroll
            for (int mf = 0; mf < 2; ++mf) {
                int row = wave * 32 + mf * 16 + (lane & 15);
                int sl = (4 * i + (lane >> 4)) ^ (row & 7);
                av[mf] = *reinterpret_cast<const short8*>(&As[row * 64 + sl * 8]);
            }
            #pragma unroll
            for (int t = 0; t < 5; ++t) {
                #pragma unroll
                for (int nf = 0; nf < 4; ++nf) {
                    int r = nf * 16 + (lane & 15);
                    int sl = (4 * i + (lane >> 4)) ^ (r & 7);
                    short8 bv = *reinterpret_cast<const short8*>(&Bs[(t * 64 + r) * 64 + sl * 8]);
                    acc[0][nf][t] = __builtin_amdgcn_mfma_f32_16x16x32_bf16(av[0], bv, acc[0][nf][t], 0, 0, 0);
                    acc[1][nf][t] = __builtin_amdgcn_mfma_f32_16x16x32_bf16(av[1], bv, acc[1][nf][t], 0, 0, 0);
                }
            }
        }
        __syncthreads();
    }

    // epilogue: combine 5 panels -> u = expm1(-quad/1024)
    #pragma unroll
    for (int mf = 0; mf < 2; ++mf) {
        #pragma unroll
        for (int nf = 0; nf < 4; ++nf) {
            int col = n0 + nf * 16 + (lane & 15);
            float lamc = lam[col], mmc = mm[col];
            const float4 vm = *reinterpret_cast<const float4*>(vmu + col * 4);
            #pragma unroll
            for (int i = 0; i < 4; ++i) {
                int brow = m0 + wave * 32 + mf * 16 + (lane >> 4) * 4 + i;
                float s0 = acc[mf][nf][0][i];
                float p0 = acc[mf][nf][1][i] - vm.x;
                float p1 = acc[mf][nf][2][i] - vm.y;
                float p2 = acc[mf][nf][3][i] - vm.z;
                float p3 = acc[mf][nf][4][i] - vm.w;
                float q = lamc * (xx[brow] - 2.f * s0 + mmc)
                        + p0 * p0 + p1 * p1 + p2 * p2 + p3 * p3;
                U[(size_t)brow * ND + col] = expm1f(-q * (1.0f / 1024.0f));
            }
        }
    }
}

// --- BN stats: per-column sum & sumsq (atomic partials) ---------------------
__global__ void colstats(const float* __restrict__ U, float* __restrict__ sum,
                         float* __restrict__ sumsq) {
    int col = blockIdx.x * 256 + threadIdx.x;   // grid.x = 4
    int r0 = blockIdx.y * 128;                  // grid.y = 32
    float s = 0.f, q = 0.f;
    for (int j = 0; j < 128; ++j) {
        float v = U[(size_t)(r0 + j) * ND + col];
        s += v; q += v * v;
    }
    atomicAdd(&sum[col], s);
    atomicAdd(&sumsq[col], q);
}

__global__ void bn_finalize(const float* __restrict__ sum, const float* __restrict__ sumsq,
                            const float* __restrict__ g, const float* __restrict__ beta,
                            float* __restrict__ A, float* __restrict__ Bsh) {
    int c = blockIdx.x * 256 + threadIdx.x;     // grid 4
    float m = sum[c] * (1.0f / 4096.0f);
    float var = sumsq[c] * (1.0f / 4096.0f) - m * m;
    float a = rsqrtf(var + 1e-5f) * g[c];
    A[c] = a;
    Bsh[c] = beta[c] - m * a;
}

// --- apply BN -> h (bf16) + row norms for layer 2 ---------------------------
__global__ void bn_apply_h(const float* __restrict__ U, const float* __restrict__ A,
                           const float* __restrict__ Bsh, ushortT* __restrict__ hh,
                           float* __restrict__ xx2) {
    __shared__ float red[4];
    int r = blockIdx.x;
    float s = 0.f;
    #pragma unroll
    for (int j = 0; j < 4; ++j) {
        int c = threadIdx.x + j * 256;
        float h = U[(size_t)r * ND + c] * A[c] + Bsh[c];
        hh[(size_t)r * ND + c] = f2bf(h);
        s += h * h;
    }
    float tot = block_sum_256(s, red);
    if (threadIdx.x == 0) xx2[r] = tot;
}

// --- apply BN2 + identity shortcut -----------------------------------------
__global__ void bn_apply_out(const float* __restrict__ U, const float* __restrict__ A,
                             const float* __restrict__ Bsh, const float* __restrict__ x,
                             float* __restrict__ out) {
    const int total = NB * ND;
    int stride = gridDim.x * blockDim.x;
    for (int i = blockIdx.x * blockDim.x + threadIdx.x; i < total; i += stride) {
        int c = i & 1023;
        out[i] = U[i] * A[c] + Bsh[c] + x[i];
    }
}

extern "C" void kernel_launch(void* const* d_in, const int* in_sizes, int n_in,
                              void* d_out, int out_size, void* d_ws, size_t ws_size,
                              hipStream_t stream) {
    const float* x    = (const float*)d_in[0];
    const float* mu1  = (const float*)d_in[1];
    const float* lam1 = (const float*)d_in[2];
    const float* v1   = (const float*)d_in[3];
    const float* g1   = (const float*)d_in[4];
    const float* b1   = (const float*)d_in[5];
    const float* mu2  = (const float*)d_in[6];
    const float* lam2 = (const float*)d_in[7];
    const float* v2   = (const float*)d_in[8];
    const float* g2   = (const float*)d_in[9];
    const float* b2   = (const float*)d_in[10];
    float* out = (float*)d_out;
    char* ws = (char*)d_ws;

    // workspace layout (bytes)
    ushortT* xh = (ushortT*)(ws + 0);                  //  8 MB
    ushortT* hh = (ushortT*)(ws + (size_t)8  * 1024 * 1024);   //  8 MB
    ushortT* W1 = (ushortT*)(ws + (size_t)16 * 1024 * 1024);   // 10 MB
    ushortT* W2 = (ushortT*)(ws + (size_t)26 * 1024 * 1024 + 262144); // 10 MB
    float*   U  = (float*)  (ws + (size_t)36 * 1024 * 1024 + 524288); // 16 MB
    char* st = ws + (size_t)52 * 1024 * 1024 + 786432;
    float* xx1   = (float*)(st + 0);
    float* xx2   = (float*)(st + 16384);
    float* mm1   = (float*)(st + 32768);
    float* mm2   = (float*)(st + 36864);
    float* vmu1  = (float*)(st + 40960);
    float* vmu2  = (float*)(st + 57344);
    float* sum1  = (float*)(st + 73728);
    float* sumsq1= (float*)(st + 77824);
    float* sum2  = (float*)(st + 81920);
    float* sumsq2= (float*)(st + 86016);
    float* A1    = (float*)(st + 90112);
    float* B1s   = (float*)(st + 94208);
    float* A2    = (float*)(st + 98304);
    float* B2s   = (float*)(st + 102400);

    const size_t needed = (size_t)52 * 1024 * 1024 + 786432 + 106496;
    if (ws_size < needed) return;  // leaves d_out poisoned -> unambiguous failure signature

    hipMemsetAsync(sum1, 0, 16384, stream);  // sum1,sumsq1,sum2,sumsq2 (contiguous)

    prep_x<<<NB, 256, 0, stream>>>(x, xh, xx1);
    prep_w<<<5120, 256, 0, stream>>>(mu1, v1, W1, mm1, vmu1);
    prep_w<<<5120, 256, 0, stream>>>(mu2, v2, W2, mm2, vmu2);

    gemm_hmu<<<512, 256, 0, stream>>>(xh, W1, xx1, mm1, vmu1, lam1, U);
    colstats<<<dim3(4, 32), 256, 0, stream>>>(U, sum1, sumsq1);
    bn_finalize<<<4, 256, 0, stream>>>(sum1, sumsq1, g1, b1, A1, B1s);
    bn_apply_h<<<NB, 256, 0, stream>>>(U, A1, B1s, hh, xx2);

    gemm_hmu<<<512, 256, 0, stream>>>(hh, W2, xx2, mm2, vmu2, lam2, U);
    colstats<<<dim3(4, 32), 256, 0, stream>>>(U, sum2, sumsq2);
    bn_finalize<<<4, 256, 0, stream>>>(sum2, sumsq2, g2, b2, A2, B2s);
    bn_apply_out<<<2048, 256, 0, stream>>>(U, A2, B2s, x, out);
}

// Round 2
// 207.847 us; speedup vs baseline: 1.1608x; 1.1608x over previous
//
#include <hip/hip_runtime.h>
#include <cstdint>
#include <cstddef>

// Problem dims (fixed by setup_inputs): b=4096, d=n=1024, k=4
#define NB 4096
#define ND 1024

typedef unsigned short ushortT;
typedef short short8 __attribute__((ext_vector_type(8)));
typedef float f32x4 __attribute__((ext_vector_type(4)));

__device__ __forceinline__ ushortT f2bf(float f) {
    unsigned u = __float_as_uint(f);
    u += 0x7FFFu + ((u >> 16) & 1u);      // round-to-nearest-even
    return (ushortT)(u >> 16);
}

__device__ __forceinline__ float block_sum_256(float v, float* red) {
    #pragma unroll
    for (int o = 32; o > 0; o >>= 1) v += __shfl_down(v, o, 64);
    int wave = threadIdx.x >> 6;
    if ((threadIdx.x & 63) == 0) red[wave] = v;
    __syncthreads();
    return red[0] + red[1] + red[2] + red[3];
}

// --- fused prep: x->bf16 + ||x||^2 ; [mu;v]->bf16 W + ||mu||^2 + v.mu ;
//     zero BN stat accumulators ------------------------------------------------
__device__ __forceinline__ void prep_x_body(const float* __restrict__ x,
                                            ushortT* __restrict__ xh,
                                            float* __restrict__ xx, int r, float* red) {
    const float* row = x + (size_t)r * ND;
    ushortT* orow = xh + (size_t)r * ND;
    float s = 0.f;
    #pragma unroll
    for (int j = 0; j < 4; ++j) {
        int c = threadIdx.x + j * 256;
        float v = row[c];
        orow[c] = f2bf(v);
        s += v * v;
    }
    float tot = block_sum_256(s, red);
    if (threadIdx.x == 0) xx[r] = tot;
}

__device__ __forceinline__ void prep_w_body(const float* __restrict__ mu,
                                            const float* __restrict__ v,
                                            ushortT* __restrict__ W,
                                            float* __restrict__ mm,
                                            float* __restrict__ vmu, int bid, float* red) {
    int t = bid >> 10;             // panel 0..4
    int n = bid & 1023;
    const float* src = (t == 0) ? (mu + (size_t)n * ND)
                                : (v + ((size_t)n * 4 + (t - 1)) * ND);
    const float* murow = mu + (size_t)n * ND;
    ushortT* dst = W + ((size_t)t * 1024 + n) * ND;
    float s = 0.f;
    #pragma unroll
    for (int j = 0; j < 4; ++j) {
        int c = threadIdx.x + j * 256;
        float val = src[c];
        dst[c] = f2bf(val);
        s += val * murow[c];
    }
    float tot = block_sum_256(s, red);
    if (threadIdx.x == 0) {
        if (t == 0) mm[n] = tot;
        else        vmu[n * 4 + (t - 1)] = tot;
    }
}

__global__ void prep_all(const float* __restrict__ x,
                         const float* __restrict__ mu1, const float* __restrict__ v1,
                         const float* __restrict__ mu2, const float* __restrict__ v2,
                         ushortT* __restrict__ xh, ushortT* __restrict__ W1,
                         ushortT* __restrict__ W2,
                         float* __restrict__ xx1,
                         float* __restrict__ mm1, float* __restrict__ vmu1,
                         float* __restrict__ mm2, float* __restrict__ vmu2,
                         float* __restrict__ statz) {
    __shared__ float red[4];
    int bid = blockIdx.x;
    if (bid < 4096)        prep_x_body(x, xh, xx1, bid, red);
    else if (bid < 9216)   prep_w_body(mu1, v1, W1, mm1, vmu1, bid - 4096, red);
    else if (bid < 14336)  prep_w_body(mu2, v2, W2, mm2, vmu2, bid - 9216, red);
    else {                 // zero sum1/sumsq1/sum2/sumsq2 (4096 floats contiguous)
        int i = (bid - 14336) * 512 + threadIdx.x * 2;
        *reinterpret_cast<float2*>(statz + i) = make_float2(0.f, 0.f);
    }
}

// --- fused 5-panel HMU GEMM + column stats ----------------------------------
// Tile: 128(M) x 64(n) x 5 panels, BK=64, 4 waves.
// Wave w owns ALL 128 rows x 16 n-cols [n0+w*16, +16) x 5 panels:
//   acc[mf][t], mf<8, t<5  (R=8, C=5 -> 13 ds_reads / 40 MFMAs per K=32)
// Staging: global_load_lds width 16, linear LDS dest, inverse-XOR-swizzled
// global source (slot s = p ^ (row&7), involution), swizzled ds_read.
__launch_bounds__(256, 2)
__global__ void gemm_hmu(const ushortT* __restrict__ Xh, const ushortT* __restrict__ Wh,
                         const float* __restrict__ xx, const float* __restrict__ mm,
                         const float* __restrict__ vmu, const float* __restrict__ lam,
                         float* __restrict__ U, float* __restrict__ sum,
                         float* __restrict__ sumsq) {
    __shared__ ushortT As[128 * 64];        // 16 KB, rows of 128B (8 slots x 16B)
    __shared__ ushortT Bs[5 * 64 * 64];     // 40 KB
    const int tid = threadIdx.x;
    const int lane = tid & 63, wave = tid >> 6;
    const int n0 = (blockIdx.x & 15) * 64;
    const int m0 = (blockIdx.x >> 4) * 128;

    f32x4 acc[8][5];
    #pragma unroll
    for (int mf = 0; mf < 8; ++mf)
        #pragma unroll
        for (int t = 0; t < 5; ++t)
            acc[mf][t] = (f32x4){0.f, 0.f, 0.f, 0.f};

    // per-lane staging geometry (constant across kt)
    const int lrow8 = lane >> 3;       // row within an 8-row chunk
    const int lp    = lane & 7;        // linear 16B slot within the row

    for (int kt = 0; kt < 16; ++kt) {
        const int k0 = kt * 64;
        // stage A: 16 chunks of 1KB (8 rows x 128B); wave handles q*4+wave
        #pragma unroll
        for (int q = 0; q < 4; ++q) {
            int chunk = q * 4 + wave;
            int row = chunk * 8 + lrow8;
            int s = lp ^ (row & 7);
            const ushortT* src = Xh + (size_t)(m0 + row) * ND + k0 + s * 8;
            __builtin_amdgcn_global_load_lds(
                (const __attribute__((address_space(1))) void*)src,
                (__attribute__((address_space(3))) void*)(As + chunk * 512), 16, 0, 0);
        }
        // stage B: 40 chunks; chunk rows are global rows of the 320-row panel stack
        #pragma unroll
        for (int q = 0; q < 10; ++q) {
            int chunk = q * 4 + wave;
            int row = chunk * 8 + lrow8;   // 0..319
            int t = row >> 6, rr = row & 63;
            int s = lp ^ (row & 7);
            const ushortT* src = Wh + ((size_t)t * 1024 + n0 + rr) * ND + k0 + s * 8;
            __builtin_amdgcn_global_load_lds(
                (const __attribute__((address_space(1))) void*)src,
                (__attribute__((address_space(3))) void*)(Bs + chunk * 512), 16, 0, 0);
        }
        __syncthreads();
        #pragma unroll
        for (int i = 0; i < 2; ++i) {       // two K=32 sub-steps
            short8 av[8];
            #pragma unroll
            for (int mf = 0; mf < 8; ++mf) {
                int row = mf * 16 + (lane & 15);
                int sl = (4 * i + (lane >> 4)) ^ (row & 7);
                av[mf] = *reinterpret_cast<const short8*>(&As[row * 64 + sl * 8]);
            }
            #pragma unroll
            for (int t = 0; t < 5; ++t) {
                int r = wave * 16 + (lane & 15);
                int sl = (4 * i + (lane >> 4)) ^ (r & 7);
                short8 bv = *reinterpret_cast<const short8*>(&Bs[(t * 64 + r) * 64 + sl * 8]);
                #pragma unroll
                for (int mf = 0; mf < 8; ++mf)
                    acc[mf][t] = __builtin_amdgcn_mfma_f32_16x16x32_bf16(av[mf], bv, acc[mf][t], 0, 0, 0);
            }
        }
        __syncthreads();
    }

    // epilogue: u = expm1(-quad/1024); fused per-column sum/sumsq partials
    const int col = n0 + wave * 16 + (lane & 15);
    const float lamc = lam[col], mmc = mm[col];
    const float4 vm = *reinterpret_cast<const float4*>(vmu + col * 4);
    float csum = 0.f, csq = 0.f;
    #pragma unroll
    for (int mf = 0; mf < 8; ++mf) {
        #pragma unroll
        for (int i = 0; i < 4; ++i) {
            int brow = m0 + mf * 16 + (lane >> 4) * 4 + i;
            float s0 = acc[mf][0][i];
            float p0 = acc[mf][1][i] - vm.x;
            float p1 = acc[mf][2][i] - vm.y;
            float p2 = acc[mf][3][i] - vm.z;
            float p3 = acc[mf][4][i] - vm.w;
            float q = lamc * (xx[brow] - 2.f * s0 + mmc)
                    + p0 * p0 + p1 * p1 + p2 * p2 + p3 * p3;
            float u = expm1f(-q * (1.0f / 1024.0f));
            U[(size_t)brow * ND + col] = u;
            csum += u; csq += u * u;
        }
    }
    csum += __shfl_xor(csum, 16); csum += __shfl_xor(csum, 32);
    csq  += __shfl_xor(csq, 16);  csq  += __shfl_xor(csq, 32);
    if (lane < 16) {
        atomicAdd(&sum[col], csum);
        atomicAdd(&sumsq[col], csq);
    }
}

// --- BN apply (finalize inlined) -> h (bf16) + row norms for layer 2 --------
__global__ void bn_apply_h(const float* __restrict__ U, const float* __restrict__ sum,
                           const float* __restrict__ sumsq, const float* __restrict__ g,
                           const float* __restrict__ beta, ushortT* __restrict__ hh,
                           float* __restrict__ xx2) {
    __shared__ float red[4];
    int r = blockIdx.x;
    float s = 0.f;
    #pragma unroll
    for (int j = 0; j < 4; ++j) {
        int c = threadIdx.x + j * 256;
        float m = sum[c] * (1.0f / 4096.0f);
        float var = sumsq[c] * (1.0f / 4096.0f) - m * m;
        float a = rsqrtf(var + 1e-5f) * g[c];
        float b = beta[c] - m * a;
        float h = U[(size_t)r * ND + c] * a + b;
        hh[(size_t)r * ND + c] = f2bf(h);
        s += h * h;
    }
    float tot = block_sum_256(s, red);
    if (threadIdx.x == 0) xx2[r] = tot;
}

// --- BN apply 2 (finalize inlined) + identity shortcut ----------------------
__global__ void bn_apply_out(const float* __restrict__ U, const float* __restrict__ sum,
                             const float* __restrict__ sumsq, const float* __restrict__ g,
                             const float* __restrict__ beta, const float* __restrict__ x,
                             float* __restrict__ out) {
    int r = blockIdx.x;
    #pragma unroll
    for (int j = 0; j < 4; ++j) {
        int c = threadIdx.x + j * 256;
        float m = sum[c] * (1.0f / 4096.0f);
        float var = sumsq[c] * (1.0f / 4096.0f) - m * m;
        float a = rsqrtf(var + 1e-5f) * g[c];
        float b = beta[c] - m * a;
        size_t idx = (size_t)r * ND + c;
        out[idx] = U[idx] * a + b + x[idx];
    }
}

extern "C" void kernel_launch(void* const* d_in, const int* in_sizes, int n_in,
                              void* d_out, int out_size, void* d_ws, size_t ws_size,
                              hipStream_t stream) {
    const float* x    = (const float*)d_in[0];
    const float* mu1  = (const float*)d_in[1];
    const float* lam1 = (const float*)d_in[2];
    const float* v1   = (const float*)d_in[3];
    const float* g1   = (const float*)d_in[4];
    const float* b1   = (const float*)d_in[5];
    const float* mu2  = (const float*)d_in[6];
    const float* lam2 = (const float*)d_in[7];
    const float* v2   = (const float*)d_in[8];
    const float* g2   = (const float*)d_in[9];
    const float* b2   = (const float*)d_in[10];
    float* out = (float*)d_out;
    char* ws = (char*)d_ws;

    // workspace layout (bytes)
    ushortT* xh = (ushortT*)(ws + 0);                                   //  8 MB
    ushortT* hh = (ushortT*)(ws + (size_t)8  * 1024 * 1024);            //  8 MB
    ushortT* W1 = (ushortT*)(ws + (size_t)16 * 1024 * 1024);            // 10 MB
    ushortT* W2 = (ushortT*)(ws + (size_t)26 * 1024 * 1024 + 262144);   // 10 MB
    float*   U  = (float*)  (ws + (size_t)36 * 1024 * 1024 + 524288);   // 16 MB
    char* st = ws + (size_t)52 * 1024 * 1024 + 786432;
    float* xx1   = (float*)(st + 0);
    float* xx2   = (float*)(st + 16384);
    float* mm1   = (float*)(st + 32768);
    float* mm2   = (float*)(st + 36864);
    float* vmu1  = (float*)(st + 40960);
    float* vmu2  = (float*)(st + 57344);
    float* sum1  = (float*)(st + 73728);   // sum1,sumsq1,sum2,sumsq2: 16KB contiguous
    float* sumsq1= (float*)(st + 77824);
    float* sum2  = (float*)(st + 81920);
    float* sumsq2= (float*)(st + 86016);

    const size_t needed = (size_t)52 * 1024 * 1024 + 786432 + 106496;
    if (ws_size < needed) return;

    prep_all<<<14344, 256, 0, stream>>>(x, mu1, v1, mu2, v2, xh, W1, W2,
                                        xx1, mm1, vmu1, mm2, vmu2, sum1);

    gemm_hmu<<<512, 256, 0, stream>>>(xh, W1, xx1, mm1, vmu1, lam1, U, sum1, sumsq1);
    bn_apply_h<<<NB, 256, 0, stream>>>(U, sum1, sumsq1, g1, b1, hh, xx2);

    gemm_hmu<<<512, 256, 0, stream>>>(hh, W2, xx2, mm2, vmu2, lam2, U, sum2, sumsq2);
    bn_apply_out<<<NB, 256, 0, stream>>>(U, sum2, sumsq2, g2, b2, x, out);
}